// Round 2
// baseline (678.395 us; speedup 1.0000x reference)
//
#include <hip/hip_runtime.h>

typedef unsigned int u32;
typedef int  v4i  __attribute__((ext_vector_type(4)));
typedef u32  u32x4 __attribute__((ext_vector_type(4)));

#define WSCALE 512.0f
#define INV16S (1.0f / 8192.0f)   // 1/(16*WSCALE)

typedef __attribute__((address_space(3))) char lds_char_t;
typedef const __attribute__((address_space(1))) char g_char_t;

// ---- weight prep: fp32 OIHW (64,64,3,3) -> int8 in A-fragment-linear order ----
// wq[((tap*4+m)*64 + lane)*16 + u] = q512(w[o=16m+(lane&15)][c=(lane>>4)*16+u][tap])
__global__ void wprep_kernel(const float* __restrict__ w, signed char* __restrict__ wq) {
  int i = blockIdx.x * 256 + threadIdx.x;
  if (i >= 36864) return;
  int u    = i & 15;
  int lane = (i >> 4) & 63;
  int m    = (i >> 10) & 3;
  int tap  = i >> 12;
  int p = lane & 15, kg = lane >> 4;
  int o = m * 16 + p, c = kg * 16 + u;
  int r = tap / 3, s = tap - 3 * r;
  float v = w[((o * 64 + c) * 3 + r) * 3 + s];
  float q = rintf(v * WSCALE);
  q = fminf(fmaxf(q, -127.0f), 127.0f);
  wq[i] = (signed char)(int)q;
}

// ---- main fused kernel: 8x16 px tile, 8 waves, 2 bit-half passes ----
__launch_bounds__(512, 4)
__global__ void conv_kernel(const float* __restrict__ x,
                            const signed char* __restrict__ wq,
                            const float* __restrict__ bias,
                            float* __restrict__ out) {
  __shared__ __align__(16) signed char   swq[36864];       // A-fragment-linear weights
  __shared__ __align__(16) unsigned char spatch[180 * 80]; // 10 rows x 18 cols, px stride 80B
  __shared__ float sbias[64];

  const int tid = threadIdx.x;
  const int bid = blockIdx.x;
  const int b   = bid / 98;            // 14 h-tiles * 7 w-tiles
  const int rem = bid - b * 98;
  const int ht  = rem / 7;
  const int wt  = rem - ht * 7;
  const int h0 = ht * 8, w0 = wt * 16;

  const int lane = tid & 63, wid = tid >> 6;

  // ---- stage weights: 36 x (64 lanes x 16B) direct global->LDS ----
  {
    const char* base = (const char*)wq;
    for (int i = wid; i < 36; i += 8) {
      __builtin_amdgcn_global_load_lds(
          (g_char_t*)(base + i * 1024 + lane * 16),
          (lds_char_t*)((char*)swq + i * 1024),
          16, 0, 0);
    }
  }
  if (tid < 64) sbias[tid] = bias[tid];

  // ---- stage patch: 180 px x 64 ch, 4 channels packed per u32 write ----
  for (int t = tid; t < 2880; t += 512) {
    int cg  = t / 180;
    int pix = t - cg * 180;
    int ph = pix / 18, pw = pix - ph * 18;
    int gh = h0 + ph, gw = w0 + pw;
    const bool ok = (gh < 112) && (gw < 112);
    const float* xp = x + ((b * 64 + cg * 4) * 112 + gh) * 112 + gw;
    u32 packed = 0;
    #pragma unroll
    for (int k = 0; k < 4; ++k) {
      float v = ok ? xp[k * 12544] : 0.0f;
      v = fminf(fmaxf(v, -128.0f), 127.0f);
      packed |= ((u32)((int)v & 255)) << (8 * k);   // trunc-toward-zero, 2's complement
    }
    *(u32*)&spatch[(ph * 18 + pw) * 80 + cg * 4] = packed;
  }
  __syncthreads();

  const int p = lane & 15, kg = lane >> 4;
  const unsigned char* patch_base = &spatch[(wid * 18 + p) * 80 + kg * 16];
  const signed char*   a_base     = &swq[lane * 16];

  float s[4][4];
  #pragma unroll
  for (int m = 0; m < 4; ++m)
    #pragma unroll
    for (int j = 0; j < 4; ++j) s[m][j] = 0.0f;

  #pragma unroll
  for (int half = 0; half < 2; ++half) {
    v4i acc[4][4];   // [bit-in-half][m]
    #pragma unroll
    for (int jb = 0; jb < 4; ++jb)
      #pragma unroll
      for (int m = 0; m < 4; ++m)
        acc[jb][m] = (v4i){0, 0, 0, 0};

    #pragma unroll
    for (int tap = 0; tap < 9; ++tap) {
      const int r = tap / 3, cs = tap - 3 * (tap / 3);
      u32x4 wb = *(const u32x4*)(patch_base + r * 1440 + cs * 80);
      u32 bb[4][4];
      #pragma unroll
      for (int jb = 0; jb < 4; ++jb) {
        const int sh = half * 4 + jb;
        bb[jb][0] = (wb[0] >> sh) & 0x01010101u;
        bb[jb][1] = (wb[1] >> sh) & 0x01010101u;
        bb[jb][2] = (wb[2] >> sh) & 0x01010101u;
        bb[jb][3] = (wb[3] >> sh) & 0x01010101u;
      }
      #pragma unroll
      for (int m = 0; m < 4; ++m) {
        v4i a = *(const v4i*)(a_base + (tap * 4 + m) * 1024);
        #pragma unroll
        for (int jb = 0; jb < 4; ++jb) {
          v4i bbv = {(int)bb[jb][0], (int)bb[jb][1], (int)bb[jb][2], (int)bb[jb][3]};
          acc[jb][m] = __builtin_amdgcn_mfma_i32_16x16x64_i8(a, bbv, acc[jb][m], 0, 0, 0);
        }
      }
    }

    // fold this bit-half: per-bit quantize + two's-complement weight
    #pragma unroll
    for (int m = 0; m < 4; ++m)
      #pragma unroll
      for (int jb = 0; jb < 4; ++jb) {
        const int bit = half * 4 + jb;
        const float pw16 = (bit < 7) ? (float)(16 << bit) : -2048.0f;
        #pragma unroll
        for (int j = 0; j < 4; ++j) {
          float q = rintf((float)acc[jb][m][j] * INV16S);
          q = fminf(fmaxf(q, -128.0f), 127.0f);
          s[m][j] = fmaf(pw16, q, s[m][j]);
        }
      }
  }

  // ---- store ----
  const int orow = h0 + wid, ocol = w0 + p;
  if (orow < 110 && ocol < 110) {
    #pragma unroll
    for (int m = 0; m < 4; ++m)
      #pragma unroll
      for (int j = 0; j < 4; ++j) {
        const int o = m * 16 + kg * 4 + j;
        out[((b * 64 + o) * 110 + orow) * 110 + ocol] = s[m][j] + sbias[o];
      }
  }
}

extern "C" void kernel_launch(void* const* d_in, const int* in_sizes, int n_in,
                              void* d_out, int out_size, void* d_ws, size_t ws_size,
                              hipStream_t stream) {
  const float* x    = (const float*)d_in[0];
  const float* w    = (const float*)d_in[1];
  const float* bias = (const float*)d_in[2];
  float* out = (float*)d_out;
  signed char* wq = (signed char*)d_ws;

  hipLaunchKernelGGL(wprep_kernel, dim3(144), dim3(256), 0, stream, w, wq);
  // grid: 16 batches x 14 h-tiles(8 rows) x 7 w-tiles(16 cols)
  hipLaunchKernelGGL(conv_kernel, dim3(16 * 14 * 7), dim3(512), 0, stream, x, wq, bias, out);
}

// Round 3
// 341.295 us; speedup vs baseline: 1.9877x; 1.9877x over previous
//
#include <hip/hip_runtime.h>

typedef unsigned int u32;
typedef int  v4i  __attribute__((ext_vector_type(4)));
typedef u32  u32x4 __attribute__((ext_vector_type(4)));

#define WSCALE 512.0f
#define INV16S (1.0f / 8192.0f)   // 1/(16*WSCALE)

typedef __attribute__((address_space(3))) char lds_char_t;
typedef const __attribute__((address_space(1))) char g_char_t;

// ---- weight prep: fp32 OIHW (64,64,3,3) -> int8 in A-fragment-linear order ----
// wq[((tap*4+m)*64 + lane)*16 + u] = q512(w[o=16m+(lane&15)][c=(lane>>4)*16+u][tap])
__global__ void wprep_kernel(const float* __restrict__ w, signed char* __restrict__ wq) {
  int i = blockIdx.x * 256 + threadIdx.x;
  if (i >= 36864) return;
  int u    = i & 15;
  int lane = (i >> 4) & 63;
  int m    = (i >> 10) & 3;
  int tap  = i >> 12;
  int p = lane & 15, kg = lane >> 4;
  int o = m * 16 + p, c = kg * 16 + u;
  int r = tap / 3, s = tap - 3 * r;
  float v = w[((o * 64 + c) * 3 + r) * 3 + s];
  float q = rintf(v * WSCALE);
  q = fminf(fmaxf(q, -127.0f), 127.0f);
  wq[i] = (signed char)(int)q;
}

// ---- main fused kernel: 8x16 px tile, 4 waves, 2 row-passes x 2 bit-half passes ----
__launch_bounds__(256, 3)
__global__ void conv_kernel(const float* __restrict__ x,
                            const signed char* __restrict__ wq,
                            const float* __restrict__ bias,
                            float* __restrict__ out) {
  __shared__ __align__(16) signed char   swq[36864];       // A-fragment-linear weights
  __shared__ __align__(16) unsigned char spatch[180 * 80]; // 10 rows x 18 cols, px stride 80B
  __shared__ float sbias[64];

  const int tid = threadIdx.x;
  const int bid = blockIdx.x;
  const int b   = bid / 98;            // 14 h-tiles * 7 w-tiles
  const int rem = bid - b * 98;
  const int ht  = rem / 7;
  const int wt  = rem - ht * 7;
  const int h0 = ht * 8, w0 = wt * 16;

  const int lane = tid & 63, wid = tid >> 6;

  // ---- stage weights: 36 x (64 lanes x 16B) direct global->LDS ----
  {
    const char* base = (const char*)wq;
    for (int i = wid; i < 36; i += 4) {
      __builtin_amdgcn_global_load_lds(
          (g_char_t*)(base + i * 1024 + lane * 16),
          (lds_char_t*)((char*)swq + i * 1024),
          16, 0, 0);
    }
  }
  if (tid < 64) sbias[tid] = bias[tid];

  // ---- stage patch: 180 px x 64 ch, 4 channels packed per u32 write ----
  for (int t = tid; t < 2880; t += 256) {
    int cg  = t / 180;
    int pix = t - cg * 180;
    int ph = pix / 18, pw = pix - ph * 18;
    int gh = h0 + ph, gw = w0 + pw;
    const bool ok = (gh < 112) && (gw < 112);
    const float* xp = x + ((b * 64 + cg * 4) * 112 + gh) * 112 + gw;
    u32 packed = 0;
    #pragma unroll
    for (int k = 0; k < 4; ++k) {
      float v = ok ? xp[k * 12544] : 0.0f;
      v = fminf(fmaxf(v, -128.0f), 127.0f);
      packed |= ((u32)((int)v & 255)) << (8 * k);   // trunc-toward-zero, 2's complement
    }
    *(u32*)&spatch[(ph * 18 + pw) * 80 + cg * 4] = packed;
  }
  __syncthreads();

  const int p = lane & 15, kg = lane >> 4;
  const signed char* a_base = &swq[lane * 16];
  const int ocol = w0 + p;

  #pragma unroll
  for (int rp = 0; rp < 2; ++rp) {
    const int prow = rp * 4 + wid;     // patch row of this wave's outputs
    const unsigned char* patch_base = &spatch[(prow * 18 + p) * 80 + kg * 16];

    float s[4][4];
    #pragma unroll
    for (int m = 0; m < 4; ++m)
      #pragma unroll
      for (int j = 0; j < 4; ++j) s[m][j] = 0.0f;

    #pragma unroll
    for (int half = 0; half < 2; ++half) {
      v4i acc[4][4];   // [bit-in-half][m]
      #pragma unroll
      for (int jb = 0; jb < 4; ++jb)
        #pragma unroll
        for (int m = 0; m < 4; ++m)
          acc[jb][m] = (v4i){0, 0, 0, 0};

      #pragma unroll
      for (int tap = 0; tap < 9; ++tap) {
        const int r = tap / 3, cs = tap - 3 * (tap / 3);
        u32x4 wb = *(const u32x4*)(patch_base + r * 1440 + cs * 80);
        u32 bb[4][4];
        #pragma unroll
        for (int jb = 0; jb < 4; ++jb) {
          const int sh = half * 4 + jb;
          bb[jb][0] = (wb[0] >> sh) & 0x01010101u;
          bb[jb][1] = (wb[1] >> sh) & 0x01010101u;
          bb[jb][2] = (wb[2] >> sh) & 0x01010101u;
          bb[jb][3] = (wb[3] >> sh) & 0x01010101u;
        }
        #pragma unroll
        for (int m = 0; m < 4; ++m) {
          v4i a = *(const v4i*)(a_base + (tap * 4 + m) * 1024);
          #pragma unroll
          for (int jb = 0; jb < 4; ++jb) {
            v4i bbv = {(int)bb[jb][0], (int)bb[jb][1], (int)bb[jb][2], (int)bb[jb][3]};
            acc[jb][m] = __builtin_amdgcn_mfma_i32_16x16x64_i8(a, bbv, acc[jb][m], 0, 0, 0);
          }
        }
      }

      // fold this bit-half: per-bit quantize + two's-complement weight
      #pragma unroll
      for (int m = 0; m < 4; ++m)
        #pragma unroll
        for (int jb = 0; jb < 4; ++jb) {
          const int bit = half * 4 + jb;
          const float pw16 = (bit < 7) ? (float)(16 << bit) : -2048.0f;
          #pragma unroll
          for (int j = 0; j < 4; ++j) {
            float q = rintf((float)acc[jb][m][j] * INV16S);
            q = fminf(fmaxf(q, -128.0f), 127.0f);
            s[m][j] = fmaf(pw16, q, s[m][j]);
          }
        }
    }

    // ---- store this row-pass ----
    const int orow = h0 + prow;
    if (orow < 110 && ocol < 110) {
      #pragma unroll
      for (int m = 0; m < 4; ++m)
        #pragma unroll
        for (int j = 0; j < 4; ++j) {
          const int o = m * 16 + kg * 4 + j;
          out[((b * 64 + o) * 110 + orow) * 110 + ocol] = s[m][j] + sbias[o];
        }
    }
  }
}

extern "C" void kernel_launch(void* const* d_in, const int* in_sizes, int n_in,
                              void* d_out, int out_size, void* d_ws, size_t ws_size,
                              hipStream_t stream) {
  const float* x    = (const float*)d_in[0];
  const float* w    = (const float*)d_in[1];
  const float* bias = (const float*)d_in[2];
  float* out = (float*)d_out;
  signed char* wq = (signed char*)d_ws;

  hipLaunchKernelGGL(wprep_kernel, dim3(144), dim3(256), 0, stream, w, wq);
  // grid: 16 batches x 14 h-tiles(8 rows) x 7 w-tiles(16 cols)
  hipLaunchKernelGGL(conv_kernel, dim3(16 * 14 * 7), dim3(256), 0, stream, x, wq, bias, out);
}

// Round 4
// 317.172 us; speedup vs baseline: 2.1389x; 1.0761x over previous
//
#include <hip/hip_runtime.h>

typedef unsigned int u32;
typedef int  v4i  __attribute__((ext_vector_type(4)));
typedef u32  u32x4 __attribute__((ext_vector_type(4)));

#define WSCALE 512.0f
#define INV16S (1.0f / 8192.0f)   // 1/(16*WSCALE)

typedef __attribute__((address_space(3))) char lds_char_t;
typedef const __attribute__((address_space(1))) char g_char_t;

// ---- weight prep: fp32 OIHW (64,64,3,3) -> int8 in A-fragment-linear order ----
// wq[((tap*4+m)*64 + lane)*16 + u] = q512(w[o=16m+(lane&15)][c=(lane>>4)*16+u][tap])
// plus 1280 B of zeros at wq+36864 (OOB load source)
__global__ void wprep_kernel(const float* __restrict__ w, signed char* __restrict__ wq) {
  int i = blockIdx.x * 256 + threadIdx.x;
  if (i < 36864) {
    int u    = i & 15;
    int lane = (i >> 4) & 63;
    int m    = (i >> 10) & 3;
    int tap  = i >> 12;
    int p = lane & 15, kg = lane >> 4;
    int o = m * 16 + p, c = kg * 16 + u;
    int r = tap / 3, s = tap - 3 * r;
    float v = w[((o * 64 + c) * 3 + r) * 3 + s];
    float q = rintf(v * WSCALE);
    q = fminf(fmaxf(q, -127.0f), 127.0f);
    wq[i] = (signed char)(int)q;
  } else if (i < 36864 + 1280) {
    wq[i] = 0;
  }
}

// ---- main fused kernel: 4x16 px tile, 4 waves, A from global(L2), patch via global_load_lds ----
__launch_bounds__(256, 3)
__global__ void conv_kernel(const float* __restrict__ x,
                            const signed char* __restrict__ wq,
                            const float* __restrict__ bias,
                            float* __restrict__ out) {
  __shared__ __align__(16) float         patchf[64 * 120];   // [c][6 rows][20 f32] = 30720 B
  __shared__ __align__(16) unsigned char patch8[108 * 80];   // [px=row*18+col][ch], stride 80 B
  __shared__ float sbias[64];

  const int tid  = threadIdx.x;
  const int lane = tid & 63, wid = tid >> 6;
  const int bid  = blockIdx.x;
  const int b    = bid / 196;          // 28 ht * 7 wt
  const int rem  = bid - b * 196;
  const int ht   = rem / 7;
  const int wt   = rem - ht * 7;
  const int h0 = ht * 4, w0 = wt * 16;

  // ---- stage fp32 patch: 1920 x 16B chunks direct global->LDS; OOB -> zero buffer ----
  {
    const char* zsrc = (const char*)(wq + 36864);
    #pragma unroll
    for (int i = 0; i < 8; ++i) {
      int cc = tid + i * 256;
      if (cc < 1920) {                        // wave-uniform (1920 % 64 == 0)
        int c    = cc / 30;
        int r2   = cc - c * 30;
        int prow = r2 / 5;
        int k    = r2 - prow * 5;
        int gh   = h0 + prow;
        const bool ok = (gh < 112) && (w0 + k * 4 < 112);
        const char* src = ok
            ? (const char*)(x + ((b * 64 + c) * 112 + gh) * 112 + w0 + k * 4)
            : zsrc;
        __builtin_amdgcn_global_load_lds((g_char_t*)src,
            (lds_char_t*)((char*)patchf + (wid * 64 + i * 256) * 16), 16, 0, 0);
      }
    }
  }
  if (tid < 64) sbias[tid] = bias[tid];
  __syncthreads();

  // ---- convert fp32 patch -> int8 [px][ch] (u32-packed, conflict-light) ----
  for (int e = tid; e < 1728; e += 256) {
    int px = e >> 4;                    // 0..107
    int cg = e & 15;
    int prow = px / 18, col = px - prow * 18;
    u32 packed = 0;
    #pragma unroll
    for (int j = 0; j < 4; ++j) {
      float v = patchf[(cg * 4 + j) * 120 + prow * 20 + col];
      v = fminf(fmaxf(v, -128.0f), 127.0f);
      packed |= ((u32)((int)v & 255)) << (8 * j);   // trunc-toward-zero, 2's complement
    }
    *(u32*)&patch8[px * 80 + cg * 4] = packed;
  }
  __syncthreads();

  const int p = lane & 15, kg = lane >> 4;
  const signed char* a_base = wq + lane * 16;       // global, L2-resident

  float sacc[4][4];
  #pragma unroll
  for (int m = 0; m < 4; ++m)
    #pragma unroll
    for (int j = 0; j < 4; ++j) sacc[m][j] = 0.0f;

  #pragma unroll 1
  for (int half = 0; half < 2; ++half) {
    v4i acc[4][4];   // [bit-in-half][m]
    #pragma unroll
    for (int jb = 0; jb < 4; ++jb)
      #pragma unroll
      for (int m = 0; m < 4; ++m)
        acc[jb][m] = (v4i){0, 0, 0, 0};

    const int sh0 = half * 4;

    #pragma unroll
    for (int tap = 0; tap < 9; ++tap) {
      const int r = tap / 3, cs = tap - 3 * (tap / 3);
      u32x4 wb = *(const u32x4*)&patch8[((wid + r) * 18 + (p + cs)) * 80 + kg * 16];
      u32 bb[4][4];
      #pragma unroll
      for (int jb = 0; jb < 4; ++jb) {
        const int sh = sh0 + jb;
        bb[jb][0] = (wb[0] >> sh) & 0x01010101u;
        bb[jb][1] = (wb[1] >> sh) & 0x01010101u;
        bb[jb][2] = (wb[2] >> sh) & 0x01010101u;
        bb[jb][3] = (wb[3] >> sh) & 0x01010101u;
      }
      #pragma unroll
      for (int m = 0; m < 4; ++m) {
        v4i a = *(const v4i*)(a_base + (tap * 4 + m) * 1024);
        #pragma unroll
        for (int jb = 0; jb < 4; ++jb) {
          v4i bbv = {(int)bb[jb][0], (int)bb[jb][1], (int)bb[jb][2], (int)bb[jb][3]};
          acc[jb][m] = __builtin_amdgcn_mfma_i32_16x16x64_i8(a, bbv, acc[jb][m], 0, 0, 0);
        }
      }
    }

    // fold this bit-half: per-bit quantize + two's-complement weight
    #pragma unroll
    for (int m = 0; m < 4; ++m)
      #pragma unroll
      for (int jb = 0; jb < 4; ++jb) {
        const int bit = sh0 + jb;
        const float pw16 = (bit < 7) ? (float)(1 << (4 + bit)) : -2048.0f;
        #pragma unroll
        for (int j = 0; j < 4; ++j) {
          float q = rintf((float)acc[jb][m][j] * INV16S);
          q = fminf(fmaxf(q, -128.0f), 127.0f);
          sacc[m][j] = fmaf(pw16, q, sacc[m][j]);
        }
      }
  }

  // ---- store ----
  const int orow = h0 + wid, ocol = w0 + p;
  if (orow < 110 && ocol < 110) {
    #pragma unroll
    for (int m = 0; m < 4; ++m)
      #pragma unroll
      for (int j = 0; j < 4; ++j) {
        const int o = m * 16 + kg * 4 + j;
        out[((b * 64 + o) * 110 + orow) * 110 + ocol] = sacc[m][j] + sbias[o];
      }
  }
}

extern "C" void kernel_launch(void* const* d_in, const int* in_sizes, int n_in,
                              void* d_out, int out_size, void* d_ws, size_t ws_size,
                              hipStream_t stream) {
  const float* x    = (const float*)d_in[0];
  const float* w    = (const float*)d_in[1];
  const float* bias = (const float*)d_in[2];
  float* out = (float*)d_out;
  signed char* wq = (signed char*)d_ws;

  hipLaunchKernelGGL(wprep_kernel, dim3(149), dim3(256), 0, stream, w, wq);
  // grid: 16 batches x 28 h-tiles(4 rows) x 7 w-tiles(16 cols)
  hipLaunchKernelGGL(conv_kernel, dim3(16 * 28 * 7), dim3(256), 0, stream, x, wq, bias, out);
}